// Round 1
// baseline (1009.797 us; speedup 1.0000x reference)
//
#include <hip/hip_runtime.h>

#define T_STEPS 64
#define INPUT_BITS 1024
#define N_STATE 2048
#define N_OUT 256
#define NB 16
#define HASHROW 65536

// Single-block sequential RAM-recurrent kernel.
// x layout (bit-packed, LDS): words [0,32) = current window (1024 bits),
//                             words [32,96) = state (2048 bits).
__global__ __launch_bounds__(1024) void ram_seq_kernel(
    const int* __restrict__ input_bits,      // [65536] in {0,1}
    const int* __restrict__ conn_state,      // [2048*16] in [0,3072)
    const int* __restrict__ conn_out,        // [256*16]  in [0,2048)
    const float* __restrict__ state_table,   // [2048*65536]
    const float* __restrict__ output_table,  // [256*65536]
    float* __restrict__ out)                 // [256]
{
    __shared__ unsigned int pk[2048];  // all 65536 input bits, packed
    __shared__ unsigned int xw[96];    // current concat vector, packed

    const int tid  = threadIdx.x;
    const int lane = tid & 63;
    const int wave = tid >> 6;   // 0..15

    // ---- one-time: pack all input bits via per-wave ballot (coalesced) ----
    for (int g = wave; g < 1024; g += 16) {            // group g = bits [g*64, g*64+64)
        int v = input_bits[g * 64 + lane];
        unsigned long long m = __ballot(v != 0);
        if (lane == 0) {
            pk[2 * g]     = (unsigned int)(m & 0xFFFFFFFFull);
            pk[2 * g + 1] = (unsigned int)(m >> 32);
        }
    }
    // zero initial state bits
    if (tid < 64) xw[32 + tid] = 0u;

    // ---- preload this thread's two neurons' connections ----
    int c0[NB], c1[NB];
#pragma unroll
    for (int j = 0; j < NB; j++) {
        c0[j] = conn_state[tid * NB + j];
        c1[j] = conn_state[(tid + 1024) * NB + j];
    }
    const float* row0 = state_table + (size_t)tid * HASHROW;
    const float* row1 = state_table + (size_t)(tid + 1024) * HASHROW;

    __syncthreads();                 // pk + state zero visible
    if (tid < 32) xw[tid] = pk[tid]; // window 0
    __syncthreads();

    // ---- 64 sequential steps ----
    for (int t = 0; t < T_STEPS; t++) {
        unsigned int a0 = 0, a1 = 0;
#pragma unroll
        for (int j = 0; j < NB; j++) {
            unsigned int b0 = (xw[c0[j] >> 5] >> (c0[j] & 31)) & 1u;
            unsigned int b1 = (xw[c1[j] >> 5] >> (c1[j] & 31)) & 1u;
            a0 |= b0 << j;
            a1 |= b1 << j;
        }
        float v0 = row0[a0];   // random 4B read, cold HBM line
        float v1 = row1[a1];

        __syncthreads();       // all xw reads of step t complete

        unsigned long long m0 = __ballot(v0 > 0.5f);  // neurons wave*64+lane
        unsigned long long m1 = __ballot(v1 > 0.5f);  // neurons 1024+wave*64+lane
        if (lane == 0) {
            xw[32 + 2 * wave]     = (unsigned int)(m0 & 0xFFFFFFFFull);
            xw[32 + 2 * wave + 1] = (unsigned int)(m0 >> 32);
            xw[64 + 2 * wave]     = (unsigned int)(m1 & 0xFFFFFFFFull);
            xw[64 + 2 * wave + 1] = (unsigned int)(m1 >> 32);
        }
        if (t < T_STEPS - 1 && tid < 32) xw[tid] = pk[(t + 1) * 32 + tid];

        __syncthreads();       // new state + next window visible
    }

    // ---- output layer on final state ----
    if (tid < N_OUT) {
        unsigned int a = 0;
#pragma unroll
        for (int j = 0; j < NB; j++) {
            int c = conn_out[tid * NB + j];           // in [0, 2048)
            unsigned int b = (xw[32 + (c >> 5)] >> (c & 31)) & 1u;
            a |= b << j;
        }
        out[tid] = output_table[(size_t)tid * HASHROW + a];
    }
}

extern "C" void kernel_launch(void* const* d_in, const int* in_sizes, int n_in,
                              void* d_out, int out_size, void* d_ws, size_t ws_size,
                              hipStream_t stream) {
    const int*   input_bits   = (const int*)d_in[0];
    const int*   conn_state   = (const int*)d_in[1];
    const int*   conn_out     = (const int*)d_in[2];
    const float* state_table  = (const float*)d_in[3];
    const float* output_table = (const float*)d_in[4];
    float*       out          = (float*)d_out;

    ram_seq_kernel<<<1, 1024, 0, stream>>>(input_bits, conn_state, conn_out,
                                           state_table, output_table, out);
}

// Round 2
// 795.228 us; speedup vs baseline: 1.2698x; 1.2698x over previous
//
#include <hip/hip_runtime.h>

#define T_STEPS 64
#define INPUT_BITS 1024
#define N_STATE 2048
#define N_OUT 256
#define NB 16
#define HASHROW 65536
#define NBLK 32

// ws layout (uint32 words):
//   [0]          barrier counter (monotonic within one launch)
//   [8..72)      state buf0 (2048 bits)
//   [72..136)    state buf1
//   [192..2240)  packed input windows (65536 bits)
#define WS_CNT  0
#define WS_BUF0 8
#define WS_BUF1 72
#define WS_PK   192
#define WS_WORDS_NEEDED 2240

// ---------------- init: pack input bits, zero barrier/state ----------------
__global__ __launch_bounds__(256) void ram_init_kernel(
    const int* __restrict__ input_bits, unsigned int* __restrict__ ws)
{
    const int tid = threadIdx.x, lane = tid & 63;
    const int gw = blockIdx.x * 4 + (tid >> 6);      // global wave 0..127
#pragma unroll
    for (int i = 0; i < 8; i++) {
        int g = gw * 8 + i;                           // bit-group 0..1023
        int v = input_bits[g * 64 + lane];
        unsigned long long m = __ballot(v != 0);
        if (lane == 0) {
            ws[WS_PK + 2 * g]     = (unsigned int)(m & 0xFFFFFFFFull);
            ws[WS_PK + 2 * g + 1] = (unsigned int)(m >> 32);
        }
    }
    if (blockIdx.x == 0 && tid < 192) ws[tid] = 0u;   // counter + both state bufs
}

// ---------------- main: 32 blocks, 64 neurons each, grid-barrier per step ----------------
__global__ __launch_bounds__(256) void ram_main_kernel(
    const int* __restrict__ conn_state,      // [2048*16] in [0,3072)
    const int* __restrict__ conn_out,        // [256*16]  in [0,2048)
    const float* __restrict__ state_table,   // [2048*65536]
    const float* __restrict__ output_table,  // [256*65536]
    unsigned int* __restrict__ ws,
    float* __restrict__ out)                 // [256]
{
    __shared__ unsigned int pk[2048];  // all packed windows
    __shared__ unsigned int xw[96];    // current concat vector: [0,32) window, [32,96) state

    const int tid = threadIdx.x, lane = tid & 63, wave = tid >> 6;
    const int b = blockIdx.x;

    // stage packed windows ws -> LDS (coalesced)
    for (int i = tid; i < 2048; i += 256) pk[i] = ws[WS_PK + i];

    // this block's 64 neurons: b*64 + lane (wave 0 does all per-step work)
    const unsigned int neuron = (unsigned int)(b * 64 + lane);
    int cn[NB];
#pragma unroll
    for (int j = 0; j < NB; j++) cn[j] = conn_state[neuron * NB + j];
    const float* row = state_table + (size_t)neuron * HASHROW;

    if (wave == 0) xw[32 + lane] = 0u;                // initial state = 0
    __syncthreads();
    if (wave == 0 && lane < 32) xw[lane] = pk[lane];  // window 0
    __syncthreads();

    unsigned int* const buf0 = ws + WS_BUF0;
    unsigned int* const buf1 = ws + WS_BUF1;
    unsigned int* const cnt  = ws + WS_CNT;

    for (int t = 0; t < T_STEPS; t++) {
        unsigned int* const bw = ((t + 1) & 1) ? buf1 : buf0;  // this step writes bw
        if (wave == 0) {
            unsigned int a = 0;
#pragma unroll
            for (int j = 0; j < NB; j++)
                a |= ((xw[cn[j] >> 5] >> (cn[j] & 31)) & 1u) << j;
            float v = row[a];                          // random cold HBM line
            unsigned long long m = __ballot(v > 0.5f);
            if (lane == 0) {
                __hip_atomic_store(&bw[2 * b],     (unsigned int)(m & 0xFFFFFFFFull),
                                   __ATOMIC_RELAXED, __HIP_MEMORY_SCOPE_AGENT);
                __hip_atomic_store(&bw[2 * b + 1], (unsigned int)(m >> 32),
                                   __ATOMIC_RELAXED, __HIP_MEMORY_SCOPE_AGENT);
            }
        }
        // ---- device-scope grid barrier (monotonic counter) ----
        __syncthreads();
        if (tid == 0) {
            __hip_atomic_fetch_add(cnt, 1u, __ATOMIC_ACQ_REL, __HIP_MEMORY_SCOPE_AGENT);
            const unsigned int target = (unsigned int)(NBLK * (t + 1));
            while (__hip_atomic_load(cnt, __ATOMIC_ACQUIRE, __HIP_MEMORY_SCOPE_AGENT) < target)
                __builtin_amdgcn_s_sleep(1);
        }
        __syncthreads();
        // ---- refresh xw: new state + next window ----
        if (wave == 0) {
            unsigned int s = __hip_atomic_load(&bw[lane], __ATOMIC_RELAXED,
                                               __HIP_MEMORY_SCOPE_AGENT);
            xw[32 + lane] = s;
            if (t < T_STEPS - 1 && lane < 32) xw[lane] = pk[(t + 1) * 32 + lane];
        }
        __syncthreads();
    }

    // ---- output layer: blocks 0..3, wave 0, one output neuron per lane ----
    if (b < 4 && wave == 0) {
        const int o = b * 64 + lane;
        unsigned int a = 0;
#pragma unroll
        for (int j = 0; j < NB; j++) {
            int c = conn_out[o * NB + j];              // in [0,2048)
            a |= ((xw[32 + (c >> 5)] >> (c & 31)) & 1u) << j;
        }
        out[o] = output_table[(size_t)o * HASHROW + a];
    }
}

// ---------------- fallback: round-1 single-block kernel (if ws too small) ----------------
__global__ __launch_bounds__(1024) void ram_seq_kernel(
    const int* __restrict__ input_bits, const int* __restrict__ conn_state,
    const int* __restrict__ conn_out, const float* __restrict__ state_table,
    const float* __restrict__ output_table, float* __restrict__ out)
{
    __shared__ unsigned int pk[2048];
    __shared__ unsigned int xw[96];
    const int tid = threadIdx.x, lane = tid & 63, wave = tid >> 6;

    for (int g = wave; g < 1024; g += 16) {
        int v = input_bits[g * 64 + lane];
        unsigned long long m = __ballot(v != 0);
        if (lane == 0) {
            pk[2 * g] = (unsigned int)(m & 0xFFFFFFFFull);
            pk[2 * g + 1] = (unsigned int)(m >> 32);
        }
    }
    if (tid < 64) xw[32 + tid] = 0u;
    int c0[NB], c1[NB];
#pragma unroll
    for (int j = 0; j < NB; j++) {
        c0[j] = conn_state[tid * NB + j];
        c1[j] = conn_state[(tid + 1024) * NB + j];
    }
    const float* row0 = state_table + (size_t)tid * HASHROW;
    const float* row1 = state_table + (size_t)(tid + 1024) * HASHROW;
    __syncthreads();
    if (tid < 32) xw[tid] = pk[tid];
    __syncthreads();
    for (int t = 0; t < T_STEPS; t++) {
        unsigned int a0 = 0, a1 = 0;
#pragma unroll
        for (int j = 0; j < NB; j++) {
            a0 |= ((xw[c0[j] >> 5] >> (c0[j] & 31)) & 1u) << j;
            a1 |= ((xw[c1[j] >> 5] >> (c1[j] & 31)) & 1u) << j;
        }
        float v0 = row0[a0], v1 = row1[a1];
        __syncthreads();
        unsigned long long m0 = __ballot(v0 > 0.5f);
        unsigned long long m1 = __ballot(v1 > 0.5f);
        if (lane == 0) {
            xw[32 + 2 * wave] = (unsigned int)(m0 & 0xFFFFFFFFull);
            xw[32 + 2 * wave + 1] = (unsigned int)(m0 >> 32);
            xw[64 + 2 * wave] = (unsigned int)(m1 & 0xFFFFFFFFull);
            xw[64 + 2 * wave + 1] = (unsigned int)(m1 >> 32);
        }
        if (t < T_STEPS - 1 && tid < 32) xw[tid] = pk[(t + 1) * 32 + tid];
        __syncthreads();
    }
    if (tid < N_OUT) {
        unsigned int a = 0;
#pragma unroll
        for (int j = 0; j < NB; j++) {
            int c = conn_out[tid * NB + j];
            a |= ((xw[32 + (c >> 5)] >> (c & 31)) & 1u) << j;
        }
        out[tid] = output_table[(size_t)tid * HASHROW + a];
    }
}

extern "C" void kernel_launch(void* const* d_in, const int* in_sizes, int n_in,
                              void* d_out, int out_size, void* d_ws, size_t ws_size,
                              hipStream_t stream) {
    const int*   input_bits   = (const int*)d_in[0];
    const int*   conn_state   = (const int*)d_in[1];
    const int*   conn_out     = (const int*)d_in[2];
    const float* state_table  = (const float*)d_in[3];
    const float* output_table = (const float*)d_in[4];
    float*       out          = (float*)d_out;

    if (ws_size >= WS_WORDS_NEEDED * sizeof(unsigned int)) {
        unsigned int* ws = (unsigned int*)d_ws;
        ram_init_kernel<<<NBLK, 256, 0, stream>>>(input_bits, ws);
        ram_main_kernel<<<NBLK, 256, 0, stream>>>(conn_state, conn_out, state_table,
                                                  output_table, ws, out);
    } else {
        ram_seq_kernel<<<1, 1024, 0, stream>>>(input_bits, conn_state, conn_out,
                                               state_table, output_table, out);
    }
}